// Round 9
// baseline (160.685 us; speedup 1.0000x reference)
//
#include <hip/hip_runtime.h>
#include <math.h>

#define T_SEQ 2048
#define NH    32
#define NKV   8
#define HS    128
#define FD    64
#define NBLK  32          // T_SEQ / 64
#define SCAN_NB 30        // k_main reads S_cum[B-2], B<=31 -> b<=29
#define EPSF  1e-12f
#define LDP   136         // LDS row pitch (bf16 elems)
#define STP   129         // ST pitch in rows (128 d rows + 1 z row)

typedef unsigned short u16;
typedef __bf16 bf16x8 __attribute__((ext_vector_type(8)));
typedef float  f32x4  __attribute__((ext_vector_type(4)));

__device__ __forceinline__ u16 f2b(float f) {
  unsigned u = __builtin_bit_cast(unsigned, f);
  return (u16)((u + 0x7fffu + ((u >> 16) & 1u)) >> 16);
}

// ws layout (bytes):
//  FKT: bf16 [NH][32 lt][128 f][64 j]     16,777,216   (tile-contiguous)
//  ST : bf16 [NH][NBLK][129 d][128 f]     33,816,576   (row128=z)
//  VT : bf16 [NKV][128 d][T key]           4,194,304
//  WT : bf16 [NH][64 f][128 d]               524,288   (q-side only)
//  KBB: bf16 [NKV][NBLK][64 k][128 d]      4,194,304
#define FKT_OFF 0
#define ST_OFF  16777216
#define VT_OFF  54525952
#define WT_OFF  58720256
#define KB_OFF  59768832

// ---------------- K1: merged prep ----------------
// 1312 blocks: [0,32) WTq transpose, [32,288) V transpose, [288,1312) K feature maps
__global__ __launch_bounds__(256) void k_prep(
    const float* __restrict__ wq, const float* __restrict__ wk,
    const float* __restrict__ vg, const float* __restrict__ kg,
    u16* __restrict__ WT, u16* __restrict__ VT,
    u16* __restrict__ FKT, u16* __restrict__ KBB)
{
  __shared__ __align__(16) u16 smem[2 * 64 * 136];   // 34816 B
  const int bx = blockIdx.x, tid = threadIdx.x;
  const int lane = tid & 63, w = tid >> 6;
  const int quad = lane >> 4, txn = lane & 15;

  if (bx < 32) {
    // ---- WTq transpose: h = bx ----
    float* sB = (float*)smem;                  // 128*68 f32 = 34816 B
    const float* src = wq + (size_t)bx * HS * FD;
    for (int idx = tid * 4; idx < 8192; idx += 1024) {
      int r = idx >> 6, c = idx & 63;
      *(float4*)(sB + r * 68 + c) = *(const float4*)(src + idx);
    }
    __syncthreads();
    u16* dst = WT + (size_t)bx * 8192;
    for (int i = 0; i < 8; ++i) {
      int ch = tid + i * 256;
      int f = ch >> 5, d4 = (ch & 31) * 4;
      ushort4 u;
      u.x = f2b(sB[(d4 + 0) * 68 + f]);
      u.y = f2b(sB[(d4 + 1) * 68 + f]);
      u.z = f2b(sB[(d4 + 2) * 68 + f]);
      u.w = f2b(sB[(d4 + 3) * 68 + f]);
      *(ushort4*)(dst + f * 128 + d4) = u;
    }
    return;
  }

  if (bx < 288) {
    // ---- V transpose: idx2 = bx-32 -> (b, kvh) ----
    const int idx2 = bx - 32;
    const int b = idx2 & 31, kvh = idx2 >> 5;
    float* sV = (float*)smem;                  // 64*129 f32 = 33024 B
    for (int idx = tid * 4; idx < 8192; idx += 1024) {
      int r = idx >> 7, c = idx & 127;
      *(float4*)(sV + r * 129 + c) = *(const float4*)(vg + (size_t)(b * 64 + r) * (NKV * HS) + kvh * HS + c);
    }
    __syncthreads();
#pragma unroll
    for (int i = 0; i < 32; ++i) {
      int d = w * 32 + i;
      VT[((size_t)(kvh * 128 + d)) * T_SEQ + b * 64 + lane] = f2b(sV[lane * 129 + d]);
    }
    return;
  }

  // ---- K feature map: j2 = bx-288 -> (lt, h) ----
  const int j2 = bx - 288;
  const int lt = j2 & 31, h = j2 >> 5;
  u16* sX = smem;              // X tile [k][d] pitch 136
  u16* sW = smem + 64 * 136;   // W^T rows [f][d] pitch 136

  // K tile f32 -> bf16 -> LDS
  const float* xbase = kg + (h >> 2) * HS;
  const int    xstr  = NKV * HS;
  for (int idx = tid * 4; idx < 8192; idx += 1024) {
    int r = idx >> 7, c = idx & 127;
    float4 v4 = *(const float4*)(xbase + (size_t)(lt * 64 + r) * xstr + c);
    ushort4 u; u.x = f2b(v4.x); u.y = f2b(v4.y); u.z = f2b(v4.z); u.w = f2b(v4.w);
    *(ushort4*)(sX + r * 136 + c) = u;
  }
  // W_k self-transpose: wk[h] is [128 d][64 f] f32; sW[f][d] bf16
  {
    const float* wsrc = wk + (size_t)h * (HS * FD);
    const int d = tid >> 1, f0 = (tid & 1) * 32;
#pragma unroll
    for (int i = 0; i < 8; ++i) {
      float4 v4 = *(const float4*)(wsrc + d * 64 + f0 + i * 4);
      sW[(f0 + i * 4 + 0) * 136 + d] = f2b(v4.x);
      sW[(f0 + i * 4 + 1) * 136 + d] = f2b(v4.y);
      sW[(f0 + i * 4 + 2) * 136 + d] = f2b(v4.z);
      sW[(f0 + i * 4 + 3) * 136 + d] = f2b(v4.w);
    }
  }
  __syncthreads();

  // dump bf16 K tile for k_main (once per kvh)
  if ((h & 3) == 0) {
    u16* ob = KBB + ((size_t)((h >> 2) * NBLK + lt)) * 8192;
    for (int i = 0; i < 4; ++i) {
      int ch = tid + i * 256;
      int row = ch >> 4, d8 = (ch & 15) * 8;
      *(uint4*)(ob + row * 128 + d8) = *(const uint4*)(sX + row * 136 + d8);
    }
  }

  const int arow = w * 16 + txn;
  const f32x4 vzero = {0.f, 0.f, 0.f, 0.f};
  f32x4 zt[4] = {vzero, vzero, vzero, vzero};
#pragma unroll
  for (int ks = 0; ks < 4; ++ks) {
    bf16x8 a = *(const bf16x8*)(sX + arow * 136 + ks * 32 + quad * 8);
#pragma unroll
    for (int nt = 0; nt < 4; ++nt) {
      bf16x8 bb = *(const bf16x8*)(sW + (nt * 16 + txn) * 136 + ks * 32 + quad * 8);
      zt[nt] = __builtin_amdgcn_mfma_f32_16x16x32_bf16(a, bb, zt[nt], 0, 0, 0);
    }
  }

  float E1[4][4], E2[4][4];
#pragma unroll
  for (int r = 0; r < 4; ++r) {
    float zv[4];
    float mx = -1e30f, mn = 1e30f;
#pragma unroll
    for (int nt = 0; nt < 4; ++nt) {
      zv[nt] = zt[nt][r];
      mx = fmaxf(mx, zv[nt]); mn = fminf(mn, zv[nt]);
    }
#pragma unroll
    for (int o = 1; o < 16; o <<= 1) {
      mx = fmaxf(mx, __shfl_xor(mx, o));
      mn = fminf(mn, __shfl_xor(mn, o));
    }
    float e1[4], e2[4], s1 = 0.f, s2 = 0.f;
#pragma unroll
    for (int nt = 0; nt < 4; ++nt) {
      e1[nt] = __expf(zv[nt] - mx); s1 += e1[nt];
      e2[nt] = __expf(mn - zv[nt]); s2 += e2[nt];
    }
#pragma unroll
    for (int o = 1; o < 16; o <<= 1) { s1 += __shfl_xor(s1, o); s2 += __shfl_xor(s2, o); }
    float r1 = 1.f / s1, r2 = 1.f / s2;
#pragma unroll
    for (int nt = 0; nt < 4; ++nt) {
      E1[r][nt] = fmaxf(e1[nt] * r1, EPSF);
      E2[r][nt] = fmaxf(e2[nt] * r2, EPSF);
    }
  }

  __syncthreads();

  // transpose into sX [128 f][64 j] pitch 68
#pragma unroll
  for (int r = 0; r < 4; ++r) {
    int j = w * 16 + quad * 4 + r;
#pragma unroll
    for (int nt = 0; nt < 4; ++nt) {
      sX[(nt * 16 + txn) * 68 + j]        = f2b(E1[r][nt]);
      sX[(nt * 16 + txn + 64) * 68 + j]   = f2b(E2[r][nt]);
    }
  }
  __syncthreads();
  // tiled FKT write: contiguous 16 KB per block
  u16* ob = FKT + ((size_t)(h * 32 + lt)) * 8192;
  for (int i = 0; i < 8; ++i) {
    int ch = tid + i * 256;
    int row = ch >> 4, j4 = (ch & 15) * 4;
    *(ushort4*)(ob + row * 64 + j4) = *(const ushort4*)(sX + row * 68 + j4);
  }
}

// ---------------- K2: fused state + prefix scan (dbuf, 1 barrier/iter, tiled FKT) ----------------
__global__ __launch_bounds__(256) void k_scan(
    const u16* __restrict__ FKT, const u16* __restrict__ VT, u16* __restrict__ ST)
{
  __shared__ __align__(16) u16 sVT[2][16 * 72];
  __shared__ __align__(16) u16 sFK[2][64 * 72];
  const int L = blockIdx.x + 8 * blockIdx.y + 16 * blockIdx.z;   // [0,512)
  const int xcd = L & 7, j = L >> 3;
  const int hsub = j & 3, fh = (j >> 2) & 1, dc = j >> 3;
  const int h = xcd * 4 + hsub;
  const int tid = threadIdx.x, lane = tid & 63, w = tid >> 6;
  const int quad = lane >> 4, txn = lane & 15;
  const bool doz = (dc == 0);

  bf16x8 vone;
#pragma unroll
  for (int jj = 0; jj < 8; ++jj) vone[jj] = (__bf16)1.0f;

  const u16* vbase = VT + ((size_t)((h >> 2) * 128 + dc * 16)) * T_SEQ;
  const u16* fbase = FKT + (size_t)(h * 32) * 8192 + fh * 4096;  // + b*8192 per iter

  const int srow = tid >> 4, sj4 = (tid & 15) * 4;
  ushort4 rv, rf[4];
  rv = *(const ushort4*)(vbase + (size_t)srow * T_SEQ + sj4);
#pragma unroll
  for (int i = 0; i < 4; ++i) {
    int ch = tid + i * 256;
    int fr = ch >> 4, fj4 = (ch & 15) * 4;
    rf[i] = *(const ushort4*)(fbase + fr * 64 + fj4);
  }

  const f32x4 vzero = {0.f, 0.f, 0.f, 0.f};
  f32x4 acc = vzero, zacc = vzero;
  int cur = 0;

  for (int b = 0; b < SCAN_NB; ++b) {
    u16* dV = sVT[cur];
    u16* dF = sFK[cur];
    *(ushort4*)(dV + srow * 72 + sj4) = rv;
#pragma unroll
    for (int i = 0; i < 4; ++i) {
      int ch = tid + i * 256;
      int fr = ch >> 4, fj4 = (ch & 15) * 4;
      *(ushort4*)(dF + fr * 72 + fj4) = rf[i];
    }
    __syncthreads();            // dbuf: single barrier per iter
    if (b + 1 < SCAN_NB) {
      rv = *(const ushort4*)(vbase + (size_t)srow * T_SEQ + (b + 1) * 64 + sj4);
#pragma unroll
      for (int i = 0; i < 4; ++i) {
        int ch = tid + i * 256;
        int fr = ch >> 4, fj4 = (ch & 15) * 4;
        rf[i] = *(const ushort4*)(fbase + (size_t)(b + 1) * 8192 + fr * 64 + fj4);
      }
    }
#pragma unroll
    for (int ks = 0; ks < 2; ++ks) {
      bf16x8 a  = *(const bf16x8*)(dV + txn * 72 + ks * 32 + quad * 8);
      bf16x8 bb = *(const bf16x8*)(dF + (w * 16 + txn) * 72 + ks * 32 + quad * 8);
      acc = __builtin_amdgcn_mfma_f32_16x16x32_bf16(a, bb, acc, 0, 0, 0);
      if (doz) zacc = __builtin_amdgcn_mfma_f32_16x16x32_bf16(vone, bb, zacc, 0, 0, 0);
    }
    u16* Sb = ST + (((size_t)(h * NBLK + b)) * STP + dc * 16) * 128 + fh * 64;
#pragma unroll
    for (int r = 0; r < 4; ++r)
      Sb[(quad * 4 + r) * 128 + w * 16 + txn] = f2b(acc[r]);
    if (doz && quad == 0)
      ST[(((size_t)(h * NBLK + b)) * STP + 128) * 128 + fh * 64 + w * 16 + txn] = f2b(zacc[0]);
    cur ^= 1;
  }
}

// ---------------- K4: main attention — big-buffer 4-phase chain, 5 barriers ----------------
// 1024 blocks, 256 threads = 4 waves; wave w owns q-rows [w*16, w*16+16)
// LDS 52.5 KB -> 3 blocks/CU; B-operand buffer holds a FULL operand set per phase:
// K[B]||K[B-1] (128 rows) -> V^T window (128 d x 128 key) -> S_cum (128 d x 128 f).
__global__ __launch_bounds__(256, 3) void k_main(
    const float* __restrict__ qg, const u16* __restrict__ KBB,
    const u16* __restrict__ WT, const u16* __restrict__ ST,
    const u16* __restrict__ VT, const float* __restrict__ wfac,
    float* __restrict__ out)
{
  __shared__ __align__(16) u16 RA[64 * LDP];    // A-operand: Q -> P -> FQ (wave-private stripes)
  __shared__ __align__(16) u16 BB[128 * LDP];   // B-operand: K-pair -> V^T -> S
  __shared__ __align__(16) u16 sz[128];         // z row of S_cum
  const int L = blockIdx.x + 32 * blockIdx.y;   // [0,1024)
  const int xcd = L & 7, jj = L >> 3;
  const int hsub = jj & 3, B = jj >> 2;
  const int h = xcd * 4 + hsub;
  const int tid = threadIdx.x;
  const int lane = tid & 63, w = tid >> 6;
  const int quad = lane >> 4, txn = lane & 15;
  const int arow = w * 16 + txn;
  const int koff = quad * 8;

  const f32x4 vzero = {0.f, 0.f, 0.f, 0.f};
  const bf16x8 bzero = {0, 0, 0, 0, 0, 0, 0, 0};

  const int kb0 = (B >= 1) ? B - 1 : 0;
  const u16* ktB = KBB + ((size_t)((h >> 2) * NBLK + B)) * 8192;
  const u16* ktP = KBB + ((size_t)((h >> 2) * NBLK + kb0)) * 8192;
  const u16* vts = VT  + (size_t)((h >> 2) * 128) * T_SEQ;
  const u16* wqt = WT  + (size_t)h * 8192;
  const u16* ssrc = ST + ((size_t)(h * NBLK + (B >= 2 ? B - 2 : 0))) * (STP * 128);

  // ---- phase 0: stage Q (wave-private) + K-pair (full 128 rows) ----
  {
    const float* qb = qg + (size_t)(B * 64 + w * 16) * (NH * HS) + h * HS;
#pragma unroll
    for (int i = 0; i < 8; ++i) {
      int idx = lane + i * 64;               // 0..511
      int r = idx >> 5, c4 = (idx & 31) * 4;
      float4 v4 = *(const float4*)(qb + (size_t)r * (NH * HS) + c4);
      ushort4 u; u.x = f2b(v4.x); u.y = f2b(v4.y); u.z = f2b(v4.z); u.w = f2b(v4.w);
      *(ushort4*)(RA + (w * 16 + r) * LDP + c4) = u;
    }
  }
#pragma unroll
  for (int i = 0; i < 8; ++i) {              // rows 0..63 = K[B], 64..127 = K[B-1]
    int idx = tid * 8 + i * 2048, rr = idx >> 7, c = idx & 127;
    const u16* src = (rr < 64) ? (ktB + rr * 128 + c) : (ktP + (rr - 64) * 128 + c);
    *(uint4*)(BB + rr * LDP + c) = *(const uint4*)(src);
  }

  // ---- z = Q·W (W direct from global) + fmap softmax (overlaps K stage latency) ----
  f32x4 zt[4] = {vzero, vzero, vzero, vzero};
  if (B >= 2) {
#pragma unroll
    for (int ks = 0; ks < 4; ++ks) {
      bf16x8 a = *(const bf16x8*)(RA + arow * LDP + ks * 32 + koff);
#pragma unroll
      for (int nt = 0; nt < 4; ++nt) {
        bf16x8 bb = *(const bf16x8*)(wqt + (nt * 16 + txn) * 128 + ks * 32 + koff);
        zt[nt] = __builtin_amdgcn_mfma_f32_16x16x32_bf16(a, bb, zt[nt], 0, 0, 0);
      }
    }
  }
  unsigned Epk[4][4];
  if (B >= 2) {
#pragma unroll
    for (int r = 0; r < 4; ++r) {
      float zv[4];
      float mx = -1e30f, mn = 1e30f;
#pragma unroll
      for (int nt = 0; nt < 4; ++nt) {
        zv[nt] = zt[nt][r];
        mx = fmaxf(mx, zv[nt]); mn = fminf(mn, zv[nt]);
      }
#pragma unroll
      for (int o = 1; o < 16; o <<= 1) {
        mx = fmaxf(mx, __shfl_xor(mx, o));
        mn = fminf(mn, __shfl_xor(mn, o));
      }
      float e1[4], e2[4], s1 = 0.f, s2 = 0.f;
#pragma unroll
      for (int nt = 0; nt < 4; ++nt) {
        e1[nt] = __expf(zv[nt] - mx); s1 += e1[nt];
        e2[nt] = __expf(mn - zv[nt]); s2 += e2[nt];
      }
#pragma unroll
      for (int o = 1; o < 16; o <<= 1) { s1 += __shfl_xor(s1, o); s2 += __shfl_xor(s2, o); }
      float r1 = 1.f / s1, r2 = 1.f / s2;
#pragma unroll
      for (int nt = 0; nt < 4; ++nt) {
        unsigned lo = f2b(fmaxf(e1[nt] * r1, EPSF));
        unsigned hi = f2b(fmaxf(e2[nt] * r2, EPSF));
        Epk[r][nt] = lo | (hi << 16);
      }
    }
  }
  __syncthreads();                           // bar1: K-pair staged

  // ---- phase 1: QK^T both blocks (32 MFMAs) ----
  f32x4 s[8];
#pragma unroll
  for (int t = 0; t < 8; ++t) s[t] = vzero;
#pragma unroll
  for (int ks = 0; ks < 4; ++ks) {
    bf16x8 a = *(const bf16x8*)(RA + arow * LDP + ks * 32 + koff);
#pragma unroll
    for (int t = 0; t < 4; ++t) {
      bf16x8 bb = *(const bf16x8*)(BB + (t * 16 + txn) * LDP + ks * 32 + koff);
      s[4 + t] = __builtin_amdgcn_mfma_f32_16x16x32_bf16(a, bb, s[4 + t], 0, 0, 0);
    }
    if (B >= 1) {
#pragma unroll
      for (int t = 0; t < 4; ++t) {
        bf16x8 bb = *(const bf16x8*)(BB + (64 + t * 16 + txn) * LDP + ks * 32 + koff);
        s[t] = __builtin_amdgcn_mfma_f32_16x16x32_bf16(a, bb, s[t], 0, 0, 0);
      }
    }
  }
  __syncthreads();                           // bar2: K reads done

  // ---- phase 2: stage V^T window (128 d x 128 key) ; softmax overlaps latency ----
#pragma unroll
  for (int i = 0; i < 8; ++i) {
    int idx = tid * 8 + i * 2048, rr = idx >> 7, c = idx & 127;
    int key = (c < 64) ? (kb0 * 64 + c) : (B * 64 + (c - 64));
    *(uint4*)(BB + rr * LDP + c) = *(const uint4*)(vts + (size_t)rr * T_SEQ + key);
  }
  float wf = wfac[h];
  wf = 1.f / (1.f + __expf(-wf));
  const float scale = 0.08838834764831845f;
  float ssum[4];
#pragma unroll
  for (int r = 0; r < 4; ++r) {
    const int irow = w * 16 + quad * 4 + r;
    float sv[8];
    float m = -1e30f;
#pragma unroll
    for (int t = 0; t < 8; ++t) {
      float x = s[t][r] * scale;
      bool msk = (t < 4) ? (B == 0) : ((t - 4) * 16 + txn > irow);
      x = msk ? -1e30f : x;
      sv[t] = x;
      m = fmaxf(m, x);
    }
#pragma unroll
    for (int o = 1; o < 16; o <<= 1) m = fmaxf(m, __shfl_xor(m, o));
    float ss = 0.f;
#pragma unroll
    for (int t = 0; t < 8; ++t) {
      float e = (sv[t] > -1e29f) ? wf * __expf(sv[t] - m) : 0.f;
      ss += e;
      RA[irow * LDP + t * 16 + txn] = f2b(e);   // P into own-wave stripe
    }
#pragma unroll
    for (int o = 1; o < 16; o <<= 1) ss += __shfl_xor(ss, o);
    ssum[r] = ss;
  }
  __syncthreads();                           // bar3: V staged (P visibility also covered)

  // ---- phase 3: PV all 8 t-tiles (32 MFMAs) ----
  f32x4 y[8];
#pragma unroll
  for (int t = 0; t < 8; ++t) y[t] = vzero;
#pragma unroll
  for (int ks = 0; ks < 4; ++ks) {
    if (B == 0 && ks < 2) continue;          // P == 0 on prev-block keys
    bf16x8 a = *(const bf16x8*)(RA + arow * LDP + ks * 32 + koff);
#pragma unroll
    for (int t = 0; t < 8; ++t) {
      bf16x8 bb = *(const bf16x8*)(BB + (t * 16 + txn) * LDP + ks * 32 + koff);
      y[t] = __builtin_amdgcn_mfma_f32_16x16x32_bf16(a, bb, y[t], 0, 0, 0);
    }
  }
  __syncthreads();                           // bar4: V reads done

  // ---- phase 4: stage S (128 d x 128 f) + sz ; FQ unpack overlaps latency ----
  float sln[4] = {0.f, 0.f, 0.f, 0.f};
  if (B >= 2) {
#pragma unroll
    for (int i = 0; i < 8; ++i) {
      int idx = tid * 8 + i * 2048, rr = idx >> 7, c = idx & 127;
      *(uint4*)(BB + rr * LDP + c) = *(const uint4*)(ssrc + rr * 128 + c);
    }
    if (tid < 32) *(ushort4*)(sz + tid * 4) = *(const ushort4*)(ssrc + 16384 + tid * 4);
#pragma unroll
    for (int r = 0; r < 4; ++r) {            // FQ unpack into own stripe (P dead)
      int row = w * 16 + quad * 4 + r;
#pragma unroll
      for (int nt = 0; nt < 4; ++nt) {
        RA[row * LDP + nt * 16 + txn]      = (u16)(Epk[r][nt] & 0xffffu);
        RA[row * LDP + 64 + nt * 16 + txn] = (u16)(Epk[r][nt] >> 16);
      }
    }
    __syncthreads();                         // bar5: S staged
    f32x4 yz = vzero;
#pragma unroll
    for (int ks = 0; ks < 4; ++ks) {
      bf16x8 a = *(const bf16x8*)(RA + arow * LDP + ks * 32 + koff);
#pragma unroll
      for (int t = 0; t < 8; ++t) {
        bf16x8 bb = *(const bf16x8*)(BB + (t * 16 + txn) * LDP + ks * 32 + koff);
        y[t] = __builtin_amdgcn_mfma_f32_16x16x32_bf16(a, bb, y[t], 0, 0, 0);
      }
      bf16x8 bz = (txn == 0) ? *(const bf16x8*)(sz + ks * 32 + koff) : bzero;
      yz = __builtin_amdgcn_mfma_f32_16x16x32_bf16(a, bz, yz, 0, 0, 0);
    }
#pragma unroll
    for (int r = 0; r < 4; ++r) sln[r] = __shfl(yz[r], lane & 48);
  }

  // ---- epilogue ----
  const size_t obase = ((size_t)h * T_SEQ + B * 64) * HS;
#pragma unroll
  for (int r = 0; r < 4; ++r) {
    float inv = 1.f / (ssum[r] + sln[r]);
    int irow = w * 16 + quad * 4 + r;
#pragma unroll
    for (int t = 0; t < 8; ++t)
      out[obase + (size_t)irow * HS + t * 16 + txn] = y[t][r] * inv;
  }
}

extern "C" void kernel_launch(void* const* d_in, const int* in_sizes, int n_in,
                              void* d_out, int out_size, void* d_ws, size_t ws_size,
                              hipStream_t stream) {
  const float* q    = (const float*)d_in[0];
  const float* k    = (const float*)d_in[1];
  const float* v    = (const float*)d_in[2];
  const float* wq   = (const float*)d_in[3];
  const float* wk   = (const float*)d_in[4];
  const float* wfac = (const float*)d_in[5];
  float* out = (float*)d_out;
  char* wsb = (char*)d_ws;

  u16* FKT = (u16*)(wsb + FKT_OFF);
  u16* ST  = (u16*)(wsb + ST_OFF);
  u16* VT  = (u16*)(wsb + VT_OFF);
  u16* WT  = (u16*)(wsb + WT_OFF);
  u16* KBB = (u16*)(wsb + KB_OFF);

  k_prep <<<dim3(1312),     256, 0, stream>>>(wq, wk, v, k, WT, VT, FKT, KBB);
  k_scan <<<dim3(8, 2, NH), 256, 0, stream>>>(FKT, VT, ST);
  k_main <<<dim3(NBLK, NH), 256, 0, stream>>>(q, KBB, WT, ST, VT, wfac, out);
}